// Round 7
// baseline (755.442 us; speedup 1.0000x reference)
//
#include <hip/hip_runtime.h>
#include <hip/hip_bf16.h>
#include <cstdint>
#include <cstddef>

// B=2,S=2048 -> N=4096 tokens, H=1024, F=2048, E=8, top-2 routing.
// fp32 in/out (runtime-detected; bf16 path kept). GEMMs: bf16 MFMA 16x16x32,
// fp32 acc. R7: barrier-free direct-load GEMMs (operands stream from L2/L3
// via global_load_dwordx4 straight into MFMA fragments; no LDS, no barriers),
// conflict-free merged transpose, atomic-free combine.
#define N_TOK 4096
#define H_DIM 1024
#define F_DIM 2048
#define E_NUM 8
#define RCAP 9216  // 2*N + E*127 rounded up to 128

typedef __attribute__((ext_vector_type(8))) short bf16x8;
typedef __attribute__((ext_vector_type(4))) float f32x4;

__device__ __forceinline__ float b2f(uint16_t u) {
  return __uint_as_float(((uint32_t)u) << 16);
}
__device__ __forceinline__ uint16_t f2b(float f) {
  uint32_t x = __float_as_uint(f);
  uint32_t r = (x + 0x7fffu + ((x >> 16) & 1u)) >> 16;
  return (uint16_t)r;
}

// ---------------- input dtype detection ----------------
__global__ __launch_bounds__(256) void detect_kernel(
    const uint16_t* __restrict__ x, int* __restrict__ flag) {
  __shared__ int cnt;
  if (threadIdx.x == 0) cnt = 0;
  __syncthreads();
  int ok = 0;
  for (int j = 0; j < 16; ++j) {
    uint16_t u = x[threadIdx.x * 16 + j];
    int e = (u >> 7) & 0xff;
    ok += (u == 0 || (e >= 96 && e <= 143)) ? 1 : 0;
  }
  atomicAdd(&cnt, ok);
  __syncthreads();
  if (threadIdx.x == 0) *flag = (cnt >= 3700) ? 1 : 0;  // 1 = bf16 inputs
}

// ---------------- router: fp32 logits, top-2 (no atomics) ----------
__global__ __launch_bounds__(256) void router_kernel(
    const void* __restrict__ xraw, const void* __restrict__ gwraw,
    const int* __restrict__ flag, void* __restrict__ dout,
    int* __restrict__ top_i, float* __restrict__ top_w) {
  int fl = *flag;
  int wave = threadIdx.x >> 6, lane = threadIdx.x & 63;
  int t = blockIdx.x * 4 + wave;  // one wave per token
  float xv[16];
  if (fl) {
    const uint16_t* xr = (const uint16_t*)xraw + (size_t)t * H_DIM + lane * 16;
    uint4 a = *(const uint4*)xr;
    uint4 b = *(const uint4*)(xr + 8);
    uint32_t w[8] = {a.x, a.y, a.z, a.w, b.x, b.y, b.z, b.w};
    for (int j = 0; j < 8; ++j) {
      xv[2 * j] = b2f((uint16_t)(w[j] & 0xffff));
      xv[2 * j + 1] = b2f((uint16_t)(w[j] >> 16));
    }
  } else {
    const float* xr = (const float*)xraw + (size_t)t * H_DIM + lane * 16;
    for (int j = 0; j < 4; ++j) {
      float4 v = ((const float4*)xr)[j];
      xv[4 * j] = v.x; xv[4 * j + 1] = v.y;
      xv[4 * j + 2] = v.z; xv[4 * j + 3] = v.w;
    }
  }
  float acc[E_NUM];
  for (int e = 0; e < E_NUM; ++e) {
    float s = 0.f;
    if (fl) {
      const uint16_t* gr =
          (const uint16_t*)gwraw + (size_t)e * H_DIM + lane * 16;
      uint4 a = *(const uint4*)gr;
      uint4 b = *(const uint4*)(gr + 8);
      uint32_t w[8] = {a.x, a.y, a.z, a.w, b.x, b.y, b.z, b.w};
      for (int j = 0; j < 8; ++j) {
        s += xv[2 * j] * b2f((uint16_t)(w[j] & 0xffff));
        s += xv[2 * j + 1] * b2f((uint16_t)(w[j] >> 16));
      }
    } else {
      const float* gr = (const float*)gwraw + (size_t)e * H_DIM + lane * 16;
      for (int j = 0; j < 4; ++j) {
        float4 v = ((const float4*)gr)[j];
        s += xv[4 * j] * v.x + xv[4 * j + 1] * v.y + xv[4 * j + 2] * v.z +
             xv[4 * j + 3] * v.w;
      }
    }
    acc[e] = s;
  }
  for (int off = 32; off >= 1; off >>= 1)
    for (int e = 0; e < E_NUM; ++e)
      acc[e] += __shfl_xor(acc[e], off, 64);
  if (lane < E_NUM) {
    size_t idx = (size_t)N_TOK * H_DIM + (size_t)t * E_NUM + lane;
    if (fl)
      ((uint16_t*)dout)[idx] = f2b(acc[lane]);
    else
      ((float*)dout)[idx] = acc[lane];
  }
  if (lane == 0) {
    int b0 = 0;
    float v0 = acc[0];
    for (int e = 1; e < E_NUM; ++e)
      if (acc[e] > v0) { v0 = acc[e]; b0 = e; }
    int b1 = (b0 == 0) ? 1 : 0;
    float v1 = acc[b1];
    for (int e = 0; e < E_NUM; ++e)
      if (e != b0 && acc[e] > v1) { v1 = acc[e]; b1 = e; }
    float w0 = 1.f / (1.f + expf(v1 - v0));  // top-2 renorm == 2-way softmax
    top_i[2 * t] = b0; top_i[2 * t + 1] = b1;
    top_w[2 * t] = w0; top_w[2 * t + 1] = 1.f - w0;
  }
}

// ------- histogram + scan + row assignment (1 block, zero contention) ------
__global__ __launch_bounds__(1024) void histscan_kernel(
    const int* __restrict__ top_i, int* __restrict__ counts,
    int* __restrict__ bases, int* __restrict__ row_of) {
  int tid = threadIdx.x;
  int lane = tid & 63, wave = tid >> 6;  // 16 waves
  int e_loc[8];
  int c[E_NUM] = {};
  for (int j = 0; j < 8; ++j) {
    int e = top_i[tid * 8 + j];
    e_loc[j] = e;
    c[e]++;
  }
  int inc[E_NUM];
  for (int k = 0; k < E_NUM; ++k) inc[k] = c[k];
  for (int off = 1; off < 64; off <<= 1) {
    for (int k = 0; k < E_NUM; ++k) {
      int v = __shfl_up(inc[k], off, 64);
      if (lane >= off) inc[k] += v;
    }
  }
  __shared__ int wtot[16][E_NUM];
  __shared__ int woff[16][E_NUM];
  __shared__ int base_s[E_NUM];
  if (lane == 63)
    for (int k = 0; k < E_NUM; ++k) wtot[wave][k] = inc[k];
  __syncthreads();
  if (tid < E_NUM) {
    int run = 0;
    for (int w = 0; w < 16; ++w) {
      woff[w][tid] = run;
      run += wtot[w][tid];
    }
    counts[tid] = run;
    wtot[0][tid] = run;
  }
  __syncthreads();
  if (tid == 0) {
    int b = 0;
    for (int e = 0; e < E_NUM; ++e) {
      bases[e] = b;
      base_s[e] = b;
      b += (wtot[0][e] + 127) & ~127;
    }
  }
  __syncthreads();
  int run[E_NUM];
  for (int k = 0; k < E_NUM; ++k)
    run[k] = base_s[k] + woff[wave][k] + inc[k] - c[k];  // exclusive prefix
  for (int j = 0; j < 8; ++j) {
    int e = e_loc[j];
    row_of[tid * 8 + j] = run[e]++;
  }
}

// ---------------- gather tokens -> contiguous bf16 rows ----------
__global__ __launch_bounds__(256) void gather_kernel(
    const void* __restrict__ xraw, const int* __restrict__ flag,
    const int* __restrict__ row_of, uint16_t* __restrict__ Xg) {
  int t = blockIdx.x;
  int rs0 = row_of[2 * t], rs1 = row_of[2 * t + 1];
  uint2 v;
  if (*flag) {
    v = ((const uint2*)((const uint16_t*)xraw + (size_t)t * H_DIM))[threadIdx.x];
  } else {
    float4 f =
        ((const float4*)((const float*)xraw + (size_t)t * H_DIM))[threadIdx.x];
    v.x = (uint32_t)f2b(f.x) | ((uint32_t)f2b(f.y) << 16);
    v.y = (uint32_t)f2b(f.z) | ((uint32_t)f2b(f.w) << 16);
  }
  ((uint2*)(Xg + (size_t)rs0 * H_DIM))[threadIdx.x] = v;
  ((uint2*)(Xg + (size_t)rs1 * H_DIM))[threadIdx.x] = v;
}

// --- merged weight transpose [E][K][N] -> [E][N][K], conflict-free LDS ---
// stride 65 (odd element stride) -> write phase contiguous, read phase banks
// spread (4a-pattern); verified by bank arithmetic.
__global__ __launch_bounds__(256) void transpose_all(
    const void* __restrict__ wu, const void* __restrict__ wg,
    const void* __restrict__ wd, const int* __restrict__ flag,
    uint16_t* __restrict__ WtU, uint16_t* __restrict__ WtG,
    uint16_t* __restrict__ WtD) {
  int z = blockIdx.z;
  int which = z >> 3, e = z & 7;
  const void* W = which == 0 ? wu : which == 1 ? wg : wd;
  uint16_t* Wt = which == 0 ? WtU : which == 1 ? WtG : WtD;
  int K = which == 2 ? F_DIM : H_DIM;
  int N = which == 2 ? H_DIM : F_DIM;
  int n0 = blockIdx.x * 64, k0 = blockIdx.y * 64;
  if (n0 >= N || k0 >= K) return;
  __shared__ uint16_t tile[64][65];
  size_t ebase = (size_t)e * K * N;
  uint16_t* Wout = Wt + ebase;
  int fl = *flag;
  int r = threadIdx.x >> 3;
  int c = (threadIdx.x & 7) * 8;
  if (fl) {
    const uint16_t* Win = (const uint16_t*)W + ebase;
    for (int it = 0; it < 2; ++it) {
      int row = r + it * 32;
      uint4 v = *(const uint4*)(Win + (size_t)(k0 + row) * N + n0 + c);
      uint32_t w[4] = {v.x, v.y, v.z, v.w};
      for (int j = 0; j < 4; ++j) {
        tile[row][c + 2 * j] = (uint16_t)(w[j] & 0xffff);
        tile[row][c + 2 * j + 1] = (uint16_t)(w[j] >> 16);
      }
    }
  } else {
    const float* Win = (const float*)W + ebase;
    for (int it = 0; it < 2; ++it) {
      int row = r + it * 32;
      const float* p = Win + (size_t)(k0 + row) * N + n0 + c;
      float4 a = ((const float4*)p)[0];
      float4 b = ((const float4*)p)[1];
      tile[row][c + 0] = f2b(a.x); tile[row][c + 1] = f2b(a.y);
      tile[row][c + 2] = f2b(a.z); tile[row][c + 3] = f2b(a.w);
      tile[row][c + 4] = f2b(b.x); tile[row][c + 5] = f2b(b.y);
      tile[row][c + 6] = f2b(b.z); tile[row][c + 7] = f2b(b.w);
    }
  }
  __syncthreads();
  for (int it = 0; it < 2; ++it) {
    int n = r + it * 32;
    uint4 o;
    o.x = (uint32_t)tile[c + 0][n] | ((uint32_t)tile[c + 1][n] << 16);
    o.y = (uint32_t)tile[c + 2][n] | ((uint32_t)tile[c + 3][n] << 16);
    o.z = (uint32_t)tile[c + 4][n] | ((uint32_t)tile[c + 5][n] << 16);
    o.w = (uint32_t)tile[c + 6][n] | ((uint32_t)tile[c + 7][n] << 16);
    *(uint4*)(Wout + (size_t)(n0 + n) * K + k0 + c) = o;
  }
}

// ---- fused up+gate GEMM, direct-load (no LDS / no barriers) ----
// phi = silu(X@Wg+bg) * (X@Wu+bu). Per wave: 64x64 out, dual acc.
__global__ __launch_bounds__(256, 2) void gemm_upgate(
    const uint16_t* __restrict__ Xg,
    const uint16_t* __restrict__ WtU, const uint16_t* __restrict__ WtG,
    const void* __restrict__ buRaw, const void* __restrict__ bgRaw,
    const int* __restrict__ flag,
    const int* __restrict__ counts, const int* __restrict__ bases,
    uint16_t* __restrict__ phi) {
  int e = blockIdx.z;
  int cnt = counts[e];
  int m0 = blockIdx.y * 128;
  if (m0 >= cnt) return;
  int n0 = blockIdx.x * 128;
  int base = bases[e];
  int wave = threadIdx.x >> 6, lane = threadIdx.x & 63;
  int wm = wave >> 1, wn = wave & 1;
  int q = lane >> 4, mr = lane & 15;

  // A fragment: A[m=mr][k=q*8+j]; B fragment: B[k=q*8+j][n=mr] from [N][K].
  const uint16_t* A = Xg + (size_t)(base + m0 + wm * 64 + mr) * H_DIM + q * 8;
  const uint16_t* BU =
      WtU + ((size_t)e * F_DIM + n0 + wn * 64 + mr) * H_DIM + q * 8;
  const uint16_t* BG =
      WtG + ((size_t)e * F_DIM + n0 + wn * 64 + mr) * H_DIM + q * 8;

  f32x4 accU[4][4] = {};
  f32x4 accG[4][4] = {};

#pragma unroll 2
  for (int k = 0; k < H_DIM; k += 32) {
    bf16x8 af[4], bu[4], bg[4];
    for (int mt = 0; mt < 4; ++mt)
      af[mt] = *(const bf16x8*)(A + (size_t)mt * 16 * H_DIM + k);
    for (int nt = 0; nt < 4; ++nt) {
      bu[nt] = *(const bf16x8*)(BU + (size_t)nt * 16 * H_DIM + k);
      bg[nt] = *(const bf16x8*)(BG + (size_t)nt * 16 * H_DIM + k);
    }
    for (int mt = 0; mt < 4; ++mt)
      for (int nt = 0; nt < 4; ++nt) {
        accU[mt][nt] = __builtin_amdgcn_mfma_f32_16x16x32_bf16(
            af[mt], bu[nt], accU[mt][nt], 0, 0, 0);
        accG[mt][nt] = __builtin_amdgcn_mfma_f32_16x16x32_bf16(
            af[mt], bg[nt], accG[mt][nt], 0, 0, 0);
      }
  }

  // C/D: col = lane&15, row = (lane>>4)*4 + reg
  int fl = *flag;
  int rbase = m0 + wm * 64;
  int cbase = n0 + wn * 64;
  for (int nt = 0; nt < 4; ++nt) {
    int col = cbase + nt * 16 + mr;
    float bu_v, bg_v;
    if (fl) {
      bu_v = b2f(((const uint16_t*)buRaw)[(size_t)e * F_DIM + col]);
      bg_v = b2f(((const uint16_t*)bgRaw)[(size_t)e * F_DIM + col]);
    } else {
      bu_v = ((const float*)buRaw)[(size_t)e * F_DIM + col];
      bg_v = ((const float*)bgRaw)[(size_t)e * F_DIM + col];
    }
    for (int mt = 0; mt < 4; ++mt) {
      int r0 = rbase + mt * 16 + q * 4;
      for (int rg = 0; rg < 4; ++rg) {
        int row = r0 + rg;
        float u = accU[mt][nt][rg] + bu_v;
        float v = accG[mt][nt][rg] + bg_v;
        float s = v / (1.f + expf(-v));  // silu
        phi[(size_t)(base + row) * F_DIM + col] = f2b(s * u);
      }
    }
  }
}

// ---- down GEMM, direct-load, non-atomic: yb[row] = phi@Wd + bd ----
__global__ __launch_bounds__(256, 3) void gemm_down(
    const uint16_t* __restrict__ phi, const uint16_t* __restrict__ WtD,
    const void* __restrict__ bdRaw, const int* __restrict__ flag,
    const int* __restrict__ counts, const int* __restrict__ bases,
    uint16_t* __restrict__ yb) {
  int e = blockIdx.z;
  int cnt = counts[e];
  int m0 = blockIdx.y * 128;
  if (m0 >= cnt) return;
  int n0 = blockIdx.x * 128;
  int base = bases[e];
  int wave = threadIdx.x >> 6, lane = threadIdx.x & 63;
  int wm = wave >> 1, wn = wave & 1;
  int q = lane >> 4, mr = lane & 15;

  const uint16_t* A = phi + (size_t)(base + m0 + wm * 64 + mr) * F_DIM + q * 8;
  const uint16_t* B =
      WtD + ((size_t)e * H_DIM + n0 + wn * 64 + mr) * F_DIM + q * 8;

  f32x4 acc[4][4] = {};

#pragma unroll 2
  for (int k = 0; k < F_DIM; k += 32) {
    bf16x8 af[4], bf[4];
    for (int mt = 0; mt < 4; ++mt)
      af[mt] = *(const bf16x8*)(A + (size_t)mt * 16 * F_DIM + k);
    for (int nt = 0; nt < 4; ++nt)
      bf[nt] = *(const bf16x8*)(B + (size_t)nt * 16 * F_DIM + k);
    for (int mt = 0; mt < 4; ++mt)
      for (int nt = 0; nt < 4; ++nt)
        acc[mt][nt] = __builtin_amdgcn_mfma_f32_16x16x32_bf16(
            af[mt], bf[nt], acc[mt][nt], 0, 0, 0);
  }

  int fl = *flag;
  int rbase = m0 + wm * 64;
  int cbase = n0 + wn * 64;
  for (int nt = 0; nt < 4; ++nt) {
    int col = cbase + nt * 16 + mr;
    float bd_v = fl ? b2f(((const uint16_t*)bdRaw)[(size_t)e * H_DIM + col])
                    : ((const float*)bdRaw)[(size_t)e * H_DIM + col];
    for (int mt = 0; mt < 4; ++mt) {
      int r0 = rbase + mt * 16 + q * 4;
      for (int rg = 0; rg < 4; ++rg) {
        int row = r0 + rg;
        yb[(size_t)(base + row) * H_DIM + col] = f2b(acc[mt][nt][rg] + bd_v);
      }
    }
  }
}

// ---- combine: out[t] = w0*yb[r0] + w1*yb[r1] (dtype per flag) ----
__global__ __launch_bounds__(256) void combine_kernel(
    const uint16_t* __restrict__ yb, const int* __restrict__ row_of,
    const float* __restrict__ top_w, const int* __restrict__ flag,
    void* __restrict__ out) {
  int t = blockIdx.x;
  int r0 = row_of[2 * t], r1 = row_of[2 * t + 1];
  float w0 = top_w[2 * t], w1 = top_w[2 * t + 1];
  int c = threadIdx.x * 4;
  uint2 a = *(const uint2*)(yb + (size_t)r0 * H_DIM + c);
  uint2 b = *(const uint2*)(yb + (size_t)r1 * H_DIM + c);
  float o0 = w0 * b2f((uint16_t)(a.x & 0xffff)) + w1 * b2f((uint16_t)(b.x & 0xffff));
  float o1 = w0 * b2f((uint16_t)(a.x >> 16)) + w1 * b2f((uint16_t)(b.x >> 16));
  float o2 = w0 * b2f((uint16_t)(a.y & 0xffff)) + w1 * b2f((uint16_t)(b.y & 0xffff));
  float o3 = w0 * b2f((uint16_t)(a.y >> 16)) + w1 * b2f((uint16_t)(b.y >> 16));
  if (*flag) {
    uint2 o;
    o.x = (uint32_t)f2b(o0) | ((uint32_t)f2b(o1) << 16);
    o.y = (uint32_t)f2b(o2) | ((uint32_t)f2b(o3) << 16);
    *(uint2*)((uint16_t*)out + (size_t)t * H_DIM + c) = o;
  } else {
    float4 o = {o0, o1, o2, o3};
    *(float4*)((float*)out + (size_t)t * H_DIM + c) = o;
  }
}

extern "C" void kernel_launch(void* const* d_in, const int* in_sizes, int n_in,
                              void* d_out, int out_size, void* d_ws, size_t ws_size,
                              hipStream_t stream) {
  const void* x = d_in[0];
  const void* gw = d_in[1];
  const void* w_up = d_in[2];
  const void* w_gate = d_in[3];
  const void* w_down = d_in[4];
  const void* b_up = d_in[5];
  const void* b_gate = d_in[6];
  const void* b_down = d_in[7];

  char* ws = (char*)d_ws;
  size_t off = 0;
  auto alloc = [&](size_t bytes) -> void* {
    void* p = ws + off;
    off += (bytes + 255) & ~(size_t)255;
    return p;
  };
  int* counts = (int*)alloc(32);
  int* bases = (int*)alloc(32);
  int* flag = (int*)alloc(32);
  int* top_i = (int*)alloc(sizeof(int) * N_TOK * 2);
  float* top_w = (float*)alloc(sizeof(float) * N_TOK * 2);
  int* row_of = (int*)alloc(sizeof(int) * N_TOK * 2);
  uint16_t* Xg = (uint16_t*)alloc((size_t)RCAP * H_DIM * 2);  // also yb
  uint16_t* phi = (uint16_t*)alloc((size_t)RCAP * F_DIM * 2);
  uint16_t* WtU = (uint16_t*)alloc((size_t)E_NUM * H_DIM * F_DIM * 2);
  uint16_t* WtG = (uint16_t*)alloc((size_t)E_NUM * H_DIM * F_DIM * 2);
  uint16_t* WtD = (uint16_t*)alloc((size_t)E_NUM * H_DIM * F_DIM * 2);

  detect_kernel<<<1, 256, 0, stream>>>((const uint16_t*)x, flag);
  transpose_all<<<dim3(32, 32, 24), 256, 0, stream>>>(w_up, w_gate, w_down,
                                                      flag, WtU, WtG, WtD);
  router_kernel<<<N_TOK / 4, 256, 0, stream>>>(x, gw, flag, d_out, top_i,
                                               top_w);
  histscan_kernel<<<1, 1024, 0, stream>>>(top_i, counts, bases, row_of);
  gather_kernel<<<N_TOK, 256, 0, stream>>>(x, flag, row_of, Xg);

  gemm_upgate<<<dim3(F_DIM / 128, 32, E_NUM), 256, 0, stream>>>(
      Xg, WtU, WtG, b_up, b_gate, flag, counts, bases, phi);
  // gemm_down overwrites Xg as yb (Xg consumed by gemm_upgate already)
  gemm_down<<<dim3(H_DIM / 128, 32, E_NUM), 256, 0, stream>>>(
      phi, WtD, b_down, flag, counts, bases, Xg);
  combine_kernel<<<N_TOK, 256, 0, stream>>>(Xg, row_of, top_w, flag, d_out);
}

// Round 8
// 631.664 us; speedup vs baseline: 1.1960x; 1.1960x over previous
//
#include <hip/hip_runtime.h>
#include <hip/hip_bf16.h>
#include <cstdint>
#include <cstddef>

// B=2,S=2048 -> N=4096 tokens, H=1024, F=2048, E=8, top-2 routing.
// fp32 in/out (runtime-detected; bf16 path kept). GEMMs: bf16 MFMA 16x16x32,
// fp32 acc, BK=64, XOR-swizzled LDS (R6 core — R7's direct-load was
// latency-bound at 10% MfmaUtil; LDS staging is the reuse/latency device).
// R8 = R6 GEMM cores + R7 scaffold (merged transpose, atomic-free combine)
// + occupancy bump (upgate 3 blocks/CU, down 4).
#define N_TOK 4096
#define H_DIM 1024
#define F_DIM 2048
#define E_NUM 8
#define RCAP 9216  // 2*N + E*127 rounded up to 128

typedef __attribute__((ext_vector_type(8))) short bf16x8;
typedef __attribute__((ext_vector_type(4))) float f32x4;

__device__ __forceinline__ float b2f(uint16_t u) {
  return __uint_as_float(((uint32_t)u) << 16);
}
__device__ __forceinline__ uint16_t f2b(float f) {
  uint32_t x = __float_as_uint(f);
  uint32_t r = (x + 0x7fffu + ((x >> 16) & 1u)) >> 16;
  return (uint16_t)r;
}

__device__ __forceinline__ void gl2lds16(const void* g, void* l) {
  __builtin_amdgcn_global_load_lds(
      (const __attribute__((address_space(1))) uint32_t*)g,
      (__attribute__((address_space(3))) uint32_t*)l, 16, 0, 0);
}

// Stage a 128x64 bf16 tile (16 KB) into LDS with XOR-swizzled 16B units.
__device__ __forceinline__ void stage_tile(const uint16_t* src, int ldK,
                                           char* lds, int wave, int lane) {
  int u = (lane & 7) ^ (lane >> 3);
  const char* s0 = (const char*)src + u * 16;
  size_t rb = (size_t)ldK * 2;
  int Rb = wave * 32 + (lane >> 3);
  for (int c = 0; c < 4; ++c) {
    gl2lds16(s0 + (size_t)(Rb + c * 8) * rb, lds + wave * 4096 + c * 1024);
  }
}

__device__ __forceinline__ bf16x8 read_frag(const char* lds, int R, int s,
                                            int q) {
  int unit = ((s << 2) + q) ^ (R & 7);
  return *(const bf16x8*)(lds + R * 128 + unit * 16);
}

// ---------------- input dtype detection ----------------
__global__ __launch_bounds__(256) void detect_kernel(
    const uint16_t* __restrict__ x, int* __restrict__ flag) {
  __shared__ int cnt;
  if (threadIdx.x == 0) cnt = 0;
  __syncthreads();
  int ok = 0;
  for (int j = 0; j < 16; ++j) {
    uint16_t u = x[threadIdx.x * 16 + j];
    int e = (u >> 7) & 0xff;
    ok += (u == 0 || (e >= 96 && e <= 143)) ? 1 : 0;
  }
  atomicAdd(&cnt, ok);
  __syncthreads();
  if (threadIdx.x == 0) *flag = (cnt >= 3700) ? 1 : 0;  // 1 = bf16 inputs
}

// ---------------- router: fp32 logits, top-2 (no atomics) ----------
__global__ __launch_bounds__(256) void router_kernel(
    const void* __restrict__ xraw, const void* __restrict__ gwraw,
    const int* __restrict__ flag, void* __restrict__ dout,
    int* __restrict__ top_i, float* __restrict__ top_w) {
  int fl = *flag;
  int wave = threadIdx.x >> 6, lane = threadIdx.x & 63;
  int t = blockIdx.x * 4 + wave;  // one wave per token
  float xv[16];
  if (fl) {
    const uint16_t* xr = (const uint16_t*)xraw + (size_t)t * H_DIM + lane * 16;
    uint4 a = *(const uint4*)xr;
    uint4 b = *(const uint4*)(xr + 8);
    uint32_t w[8] = {a.x, a.y, a.z, a.w, b.x, b.y, b.z, b.w};
    for (int j = 0; j < 8; ++j) {
      xv[2 * j] = b2f((uint16_t)(w[j] & 0xffff));
      xv[2 * j + 1] = b2f((uint16_t)(w[j] >> 16));
    }
  } else {
    const float* xr = (const float*)xraw + (size_t)t * H_DIM + lane * 16;
    for (int j = 0; j < 4; ++j) {
      float4 v = ((const float4*)xr)[j];
      xv[4 * j] = v.x; xv[4 * j + 1] = v.y;
      xv[4 * j + 2] = v.z; xv[4 * j + 3] = v.w;
    }
  }
  float acc[E_NUM];
  for (int e = 0; e < E_NUM; ++e) {
    float s = 0.f;
    if (fl) {
      const uint16_t* gr =
          (const uint16_t*)gwraw + (size_t)e * H_DIM + lane * 16;
      uint4 a = *(const uint4*)gr;
      uint4 b = *(const uint4*)(gr + 8);
      uint32_t w[8] = {a.x, a.y, a.z, a.w, b.x, b.y, b.z, b.w};
      for (int j = 0; j < 8; ++j) {
        s += xv[2 * j] * b2f((uint16_t)(w[j] & 0xffff));
        s += xv[2 * j + 1] * b2f((uint16_t)(w[j] >> 16));
      }
    } else {
      const float* gr = (const float*)gwraw + (size_t)e * H_DIM + lane * 16;
      for (int j = 0; j < 4; ++j) {
        float4 v = ((const float4*)gr)[j];
        s += xv[4 * j] * v.x + xv[4 * j + 1] * v.y + xv[4 * j + 2] * v.z +
             xv[4 * j + 3] * v.w;
      }
    }
    acc[e] = s;
  }
  for (int off = 32; off >= 1; off >>= 1)
    for (int e = 0; e < E_NUM; ++e)
      acc[e] += __shfl_xor(acc[e], off, 64);
  if (lane < E_NUM) {
    size_t idx = (size_t)N_TOK * H_DIM + (size_t)t * E_NUM + lane;
    if (fl)
      ((uint16_t*)dout)[idx] = f2b(acc[lane]);
    else
      ((float*)dout)[idx] = acc[lane];
  }
  if (lane == 0) {
    int b0 = 0;
    float v0 = acc[0];
    for (int e = 1; e < E_NUM; ++e)
      if (acc[e] > v0) { v0 = acc[e]; b0 = e; }
    int b1 = (b0 == 0) ? 1 : 0;
    float v1 = acc[b1];
    for (int e = 0; e < E_NUM; ++e)
      if (e != b0 && acc[e] > v1) { v1 = acc[e]; b1 = e; }
    float w0 = 1.f / (1.f + expf(v1 - v0));  // top-2 renorm == 2-way softmax
    top_i[2 * t] = b0; top_i[2 * t + 1] = b1;
    top_w[2 * t] = w0; top_w[2 * t + 1] = 1.f - w0;
  }
}

// ------- histogram + scan + row assignment (1 block, zero contention) ------
__global__ __launch_bounds__(1024) void histscan_kernel(
    const int* __restrict__ top_i, int* __restrict__ counts,
    int* __restrict__ bases, int* __restrict__ row_of) {
  int tid = threadIdx.x;
  int lane = tid & 63, wave = tid >> 6;  // 16 waves
  int e_loc[8];
  int c[E_NUM] = {};
  for (int j = 0; j < 8; ++j) {
    int e = top_i[tid * 8 + j];
    e_loc[j] = e;
    c[e]++;
  }
  int inc[E_NUM];
  for (int k = 0; k < E_NUM; ++k) inc[k] = c[k];
  for (int off = 1; off < 64; off <<= 1) {
    for (int k = 0; k < E_NUM; ++k) {
      int v = __shfl_up(inc[k], off, 64);
      if (lane >= off) inc[k] += v;
    }
  }
  __shared__ int wtot[16][E_NUM];
  __shared__ int woff[16][E_NUM];
  __shared__ int base_s[E_NUM];
  if (lane == 63)
    for (int k = 0; k < E_NUM; ++k) wtot[wave][k] = inc[k];
  __syncthreads();
  if (tid < E_NUM) {
    int run = 0;
    for (int w = 0; w < 16; ++w) {
      woff[w][tid] = run;
      run += wtot[w][tid];
    }
    counts[tid] = run;
    wtot[0][tid] = run;
  }
  __syncthreads();
  if (tid == 0) {
    int b = 0;
    for (int e = 0; e < E_NUM; ++e) {
      bases[e] = b;
      base_s[e] = b;
      b += (wtot[0][e] + 127) & ~127;
    }
  }
  __syncthreads();
  int run[E_NUM];
  for (int k = 0; k < E_NUM; ++k)
    run[k] = base_s[k] + woff[wave][k] + inc[k] - c[k];  // exclusive prefix
  for (int j = 0; j < 8; ++j) {
    int e = e_loc[j];
    row_of[tid * 8 + j] = run[e]++;
  }
}

// ---------------- gather tokens -> contiguous bf16 rows ----------
__global__ __launch_bounds__(256) void gather_kernel(
    const void* __restrict__ xraw, const int* __restrict__ flag,
    const int* __restrict__ row_of, uint16_t* __restrict__ Xg) {
  int t = blockIdx.x;
  int rs0 = row_of[2 * t], rs1 = row_of[2 * t + 1];
  uint2 v;
  if (*flag) {
    v = ((const uint2*)((const uint16_t*)xraw + (size_t)t * H_DIM))[threadIdx.x];
  } else {
    float4 f =
        ((const float4*)((const float*)xraw + (size_t)t * H_DIM))[threadIdx.x];
    v.x = (uint32_t)f2b(f.x) | ((uint32_t)f2b(f.y) << 16);
    v.y = (uint32_t)f2b(f.z) | ((uint32_t)f2b(f.w) << 16);
  }
  ((uint2*)(Xg + (size_t)rs0 * H_DIM))[threadIdx.x] = v;
  ((uint2*)(Xg + (size_t)rs1 * H_DIM))[threadIdx.x] = v;
}

// --- merged weight transpose [E][K][N] -> [E][N][K], conflict-free LDS ---
__global__ __launch_bounds__(256) void transpose_all(
    const void* __restrict__ wu, const void* __restrict__ wg,
    const void* __restrict__ wd, const int* __restrict__ flag,
    uint16_t* __restrict__ WtU, uint16_t* __restrict__ WtG,
    uint16_t* __restrict__ WtD) {
  int z = blockIdx.z;
  int which = z >> 3, e = z & 7;
  const void* W = which == 0 ? wu : which == 1 ? wg : wd;
  uint16_t* Wt = which == 0 ? WtU : which == 1 ? WtG : WtD;
  int K = which == 2 ? F_DIM : H_DIM;
  int N = which == 2 ? H_DIM : F_DIM;
  int n0 = blockIdx.x * 64, k0 = blockIdx.y * 64;
  if (n0 >= N || k0 >= K) return;
  __shared__ uint16_t tile[64][65];
  size_t ebase = (size_t)e * K * N;
  uint16_t* Wout = Wt + ebase;
  int fl = *flag;
  int r = threadIdx.x >> 3;
  int c = (threadIdx.x & 7) * 8;
  if (fl) {
    const uint16_t* Win = (const uint16_t*)W + ebase;
    for (int it = 0; it < 2; ++it) {
      int row = r + it * 32;
      uint4 v = *(const uint4*)(Win + (size_t)(k0 + row) * N + n0 + c);
      uint32_t w[4] = {v.x, v.y, v.z, v.w};
      for (int j = 0; j < 4; ++j) {
        tile[row][c + 2 * j] = (uint16_t)(w[j] & 0xffff);
        tile[row][c + 2 * j + 1] = (uint16_t)(w[j] >> 16);
      }
    }
  } else {
    const float* Win = (const float*)W + ebase;
    for (int it = 0; it < 2; ++it) {
      int row = r + it * 32;
      const float* p = Win + (size_t)(k0 + row) * N + n0 + c;
      float4 a = ((const float4*)p)[0];
      float4 b = ((const float4*)p)[1];
      tile[row][c + 0] = f2b(a.x); tile[row][c + 1] = f2b(a.y);
      tile[row][c + 2] = f2b(a.z); tile[row][c + 3] = f2b(a.w);
      tile[row][c + 4] = f2b(b.x); tile[row][c + 5] = f2b(b.y);
      tile[row][c + 6] = f2b(b.z); tile[row][c + 7] = f2b(b.w);
    }
  }
  __syncthreads();
  for (int it = 0; it < 2; ++it) {
    int n = r + it * 32;
    uint4 o;
    o.x = (uint32_t)tile[c + 0][n] | ((uint32_t)tile[c + 1][n] << 16);
    o.y = (uint32_t)tile[c + 2][n] | ((uint32_t)tile[c + 3][n] << 16);
    o.z = (uint32_t)tile[c + 4][n] | ((uint32_t)tile[c + 5][n] << 16);
    o.w = (uint32_t)tile[c + 6][n] | ((uint32_t)tile[c + 7][n] << 16);
    *(uint4*)(Wout + (size_t)(n0 + n) * K + k0 + c) = o;
  }
}

// ------------- fused up+gate GEMM: phi = silu(X@Wg+bg) * (X@Wu+bu) ---------
// 128x128 tile, BK=64, 48 KB LDS, dual accumulators, one phi write.
__global__ __launch_bounds__(256, 3) void gemm_upgate(
    const uint16_t* __restrict__ Xg,
    const uint16_t* __restrict__ WtU, const uint16_t* __restrict__ WtG,
    const void* __restrict__ buRaw, const void* __restrict__ bgRaw,
    const int* __restrict__ flag,
    const int* __restrict__ counts, const int* __restrict__ bases,
    uint16_t* __restrict__ phi) {
  int e = blockIdx.z;
  int cnt = counts[e];
  int m0 = blockIdx.y * 128;
  if (m0 >= cnt) return;
  int n0 = blockIdx.x * 128;
  int base = bases[e];
  const uint16_t* A = Xg + (size_t)(base + m0) * H_DIM;
  const uint16_t* BU = WtU + (size_t)e * F_DIM * H_DIM + (size_t)n0 * H_DIM;
  const uint16_t* BG = WtG + (size_t)e * F_DIM * H_DIM + (size_t)n0 * H_DIM;

  __shared__ __align__(16) char lA[128 * 128];
  __shared__ __align__(16) char lBu[128 * 128];
  __shared__ __align__(16) char lBg[128 * 128];

  int tid = threadIdx.x;
  int wave = tid >> 6, lane = tid & 63;
  int wm = wave >> 1, wn = wave & 1;
  int q = lane >> 4, mr = lane & 15;

  f32x4 accU[4][4] = {};
  f32x4 accG[4][4] = {};

  for (int k0 = 0; k0 < H_DIM; k0 += 64) {
    __syncthreads();
    stage_tile(A + k0, H_DIM, lA, wave, lane);
    stage_tile(BU + k0, H_DIM, lBu, wave, lane);
    stage_tile(BG + k0, H_DIM, lBg, wave, lane);
    __syncthreads();
    for (int s = 0; s < 2; ++s) {
      bf16x8 af[4], bu[4], bg[4];
      for (int mt = 0; mt < 4; ++mt)
        af[mt] = read_frag(lA, wm * 64 + mt * 16 + mr, s, q);
      for (int nt = 0; nt < 4; ++nt) {
        bu[nt] = read_frag(lBu, wn * 64 + nt * 16 + mr, s, q);
        bg[nt] = read_frag(lBg, wn * 64 + nt * 16 + mr, s, q);
      }
      for (int mt = 0; mt < 4; ++mt)
        for (int nt = 0; nt < 4; ++nt) {
          accU[mt][nt] = __builtin_amdgcn_mfma_f32_16x16x32_bf16(
              af[mt], bu[nt], accU[mt][nt], 0, 0, 0);
          accG[mt][nt] = __builtin_amdgcn_mfma_f32_16x16x32_bf16(
              af[mt], bg[nt], accG[mt][nt], 0, 0, 0);
        }
    }
  }

  int fl = *flag;
  int rbase = m0 + wm * 64;
  int cbase = n0 + wn * 64;
  for (int nt = 0; nt < 4; ++nt) {
    int col = cbase + nt * 16 + mr;
    float bu_v, bg_v;
    if (fl) {
      bu_v = b2f(((const uint16_t*)buRaw)[(size_t)e * F_DIM + col]);
      bg_v = b2f(((const uint16_t*)bgRaw)[(size_t)e * F_DIM + col]);
    } else {
      bu_v = ((const float*)buRaw)[(size_t)e * F_DIM + col];
      bg_v = ((const float*)bgRaw)[(size_t)e * F_DIM + col];
    }
    for (int mt = 0; mt < 4; ++mt) {
      int r0 = rbase + mt * 16 + q * 4;
      for (int rg = 0; rg < 4; ++rg) {
        int row = r0 + rg;
        float u = accU[mt][nt][rg] + bu_v;
        float v = accG[mt][nt][rg] + bg_v;
        float s = v / (1.f + expf(-v));  // silu
        phi[(size_t)(base + row) * F_DIM + col] = f2b(s * u);
      }
    }
  }
}

// ---- down GEMM (LDS core), non-atomic: yb[row] = phi@Wd + bd ----
__global__ __launch_bounds__(256, 4) void gemm_down(
    const uint16_t* __restrict__ phi, const uint16_t* __restrict__ WtD,
    const void* __restrict__ bdRaw, const int* __restrict__ flag,
    const int* __restrict__ counts, const int* __restrict__ bases,
    uint16_t* __restrict__ yb) {
  int e = blockIdx.z;
  int cnt = counts[e];
  int m0 = blockIdx.y * 128;
  if (m0 >= cnt) return;
  int n0 = blockIdx.x * 128;
  int base = bases[e];
  const uint16_t* A = phi + (size_t)(base + m0) * F_DIM;
  const uint16_t* B = WtD + (size_t)e * H_DIM * F_DIM + (size_t)n0 * F_DIM;

  __shared__ __align__(16) char lA[128 * 128];
  __shared__ __align__(16) char lB[128 * 128];

  int tid = threadIdx.x;
  int wave = tid >> 6, lane = tid & 63;
  int wm = wave >> 1, wn = wave & 1;
  int q = lane >> 4, mr = lane & 15;

  f32x4 acc[4][4] = {};

  for (int k0 = 0; k0 < F_DIM; k0 += 64) {
    __syncthreads();
    stage_tile(A + k0, F_DIM, lA, wave, lane);
    stage_tile(B + k0, F_DIM, lB, wave, lane);
    __syncthreads();
    for (int s = 0; s < 2; ++s) {
      bf16x8 af[4], bf[4];
      for (int mt = 0; mt < 4; ++mt)
        af[mt] = read_frag(lA, wm * 64 + mt * 16 + mr, s, q);
      for (int nt = 0; nt < 4; ++nt)
        bf[nt] = read_frag(lB, wn * 64 + nt * 16 + mr, s, q);
      for (int mt = 0; mt < 4; ++mt)
        for (int nt = 0; nt < 4; ++nt)
          acc[mt][nt] = __builtin_amdgcn_mfma_f32_16x16x32_bf16(
              af[mt], bf[nt], acc[mt][nt], 0, 0, 0);
    }
  }

  int fl = *flag;
  int rbase = m0 + wm * 64;
  int cbase = n0 + wn * 64;
  for (int nt = 0; nt < 4; ++nt) {
    int col = cbase + nt * 16 + mr;
    float bd_v = fl ? b2f(((const uint16_t*)bdRaw)[(size_t)e * H_DIM + col])
                    : ((const float*)bdRaw)[(size_t)e * H_DIM + col];
    for (int mt = 0; mt < 4; ++mt) {
      int r0 = rbase + mt * 16 + q * 4;
      for (int rg = 0; rg < 4; ++rg) {
        int row = r0 + rg;
        yb[(size_t)(base + row) * H_DIM + col] = f2b(acc[mt][nt][rg] + bd_v);
      }
    }
  }
}

// ---- combine: out[t] = w0*yb[r0] + w1*yb[r1] (dtype per flag) ----
__global__ __launch_bounds__(256) void combine_kernel(
    const uint16_t* __restrict__ yb, const int* __restrict__ row_of,
    const float* __restrict__ top_w, const int* __restrict__ flag,
    void* __restrict__ out) {
  int t = blockIdx.x;
  int r0 = row_of[2 * t], r1 = row_of[2 * t + 1];
  float w0 = top_w[2 * t], w1 = top_w[2 * t + 1];
  int c = threadIdx.x * 4;
  uint2 a = *(const uint2*)(yb + (size_t)r0 * H_DIM + c);
  uint2 b = *(const uint2*)(yb + (size_t)r1 * H_DIM + c);
  float o0 = w0 * b2f((uint16_t)(a.x & 0xffff)) + w1 * b2f((uint16_t)(b.x & 0xffff));
  float o1 = w0 * b2f((uint16_t)(a.x >> 16)) + w1 * b2f((uint16_t)(b.x >> 16));
  float o2 = w0 * b2f((uint16_t)(a.y & 0xffff)) + w1 * b2f((uint16_t)(b.y & 0xffff));
  float o3 = w0 * b2f((uint16_t)(a.y >> 16)) + w1 * b2f((uint16_t)(b.y >> 16));
  if (*flag) {
    uint2 o;
    o.x = (uint32_t)f2b(o0) | ((uint32_t)f2b(o1) << 16);
    o.y = (uint32_t)f2b(o2) | ((uint32_t)f2b(o3) << 16);
    *(uint2*)((uint16_t*)out + (size_t)t * H_DIM + c) = o;
  } else {
    float4 o = {o0, o1, o2, o3};
    *(float4*)((float*)out + (size_t)t * H_DIM + c) = o;
  }
}

extern "C" void kernel_launch(void* const* d_in, const int* in_sizes, int n_in,
                              void* d_out, int out_size, void* d_ws, size_t ws_size,
                              hipStream_t stream) {
  const void* x = d_in[0];
  const void* gw = d_in[1];
  const void* w_up = d_in[2];
  const void* w_gate = d_in[3];
  const void* w_down = d_in[4];
  const void* b_up = d_in[5];
  const void* b_gate = d_in[6];
  const void* b_down = d_in[7];

  char* ws = (char*)d_ws;
  size_t off = 0;
  auto alloc = [&](size_t bytes) -> void* {
    void* p = ws + off;
    off += (bytes + 255) & ~(size_t)255;
    return p;
  };
  int* counts = (int*)alloc(32);
  int* bases = (int*)alloc(32);
  int* flag = (int*)alloc(32);
  int* top_i = (int*)alloc(sizeof(int) * N_TOK * 2);
  float* top_w = (float*)alloc(sizeof(float) * N_TOK * 2);
  int* row_of = (int*)alloc(sizeof(int) * N_TOK * 2);
  uint16_t* Xg = (uint16_t*)alloc((size_t)RCAP * H_DIM * 2);  // also yb
  uint16_t* phi = (uint16_t*)alloc((size_t)RCAP * F_DIM * 2);
  uint16_t* WtU = (uint16_t*)alloc((size_t)E_NUM * H_DIM * F_DIM * 2);
  uint16_t* WtG = (uint16_t*)alloc((size_t)E_NUM * H_DIM * F_DIM * 2);
  uint16_t* WtD = (uint16_t*)alloc((size_t)E_NUM * H_DIM * F_DIM * 2);

  detect_kernel<<<1, 256, 0, stream>>>((const uint16_t*)x, flag);
  transpose_all<<<dim3(32, 32, 24), 256, 0, stream>>>(w_up, w_gate, w_down,
                                                      flag, WtU, WtG, WtD);
  router_kernel<<<N_TOK / 4, 256, 0, stream>>>(x, gw, flag, d_out, top_i,
                                               top_w);
  histscan_kernel<<<1, 1024, 0, stream>>>(top_i, counts, bases, row_of);
  gather_kernel<<<N_TOK, 256, 0, stream>>>(x, flag, row_of, Xg);

  gemm_upgate<<<dim3(F_DIM / 128, 32, E_NUM), 256, 0, stream>>>(
      Xg, WtU, WtG, b_up, b_gate, flag, counts, bases, phi);
  // gemm_down overwrites Xg as yb (Xg consumed by gemm_upgate already)
  gemm_down<<<dim3(H_DIM / 128, 32, E_NUM), 256, 0, stream>>>(
      phi, WtD, b_down, flag, counts, bases, Xg);
  combine_kernel<<<N_TOK, 256, 0, stream>>>(Xg, row_of, top_w, flag, d_out);
}